// Round 17
// baseline (129.362 us; speedup 1.0000x reference)
//
#include <hip/hip_runtime.h>
#include <hip/hip_bf16.h>
#include <stdint.h>
#include <stddef.h>

// Problem constants (from reference)
#define IN_F     1024
#define OUT_F    1024
#define BATCH    4096
#define NSPLINE  8            // GRID_SIZE + SPLINE_ORDER
#define KDIM     (IN_F * 9)   // 9216 : plane 0 = silu(x), planes 1..8 = spline basis
#define GRIDPTS  12           // GRID_SIZE + 2*SPLINE_ORDER + 1

typedef __bf16 bf16;
typedef __bf16 bf16x2 __attribute__((ext_vector_type(2)));
typedef __bf16 bf16x8 __attribute__((ext_vector_type(8)));
typedef float  f32x4  __attribute__((ext_vector_type(4)));

// -------------------------------------------------------------------------
// Kernel 1 (fused prep), vectorized bf16x2 stores (r15, verified).
// -------------------------------------------------------------------------
#define NB_BUILD (BATCH * IN_F / 512)   // 8192
#define NB_PACK  (OUT_F * IN_F / 512)   // 2048

__global__ __launch_bounds__(256) void prep(const float* __restrict__ x,
                                            const float* __restrict__ grid,
                                            const float* __restrict__ bw,
                                            const float* __restrict__ sw,
                                            const float* __restrict__ sc,
                                            bf16* __restrict__ A,
                                            bf16* __restrict__ W)
{
    __shared__ float g[GRIDPTS];
    __shared__ float rec[33];   // rec[(k-1)*11 + j] = 1/(g[j+k]-g[j]+1e-8)

    if (blockIdx.x < NB_BUILD) {
        // ---------------- build_A (2 elements/thread) ----------------
        if (threadIdx.x < GRIDPTS) g[threadIdx.x] = grid[threadIdx.x];  // row 0
        __syncthreads();
        if (threadIdx.x < 33) {
            const int k = threadIdx.x / 11 + 1;
            const int j = threadIdx.x % 11;
            if (j + k <= 11) rec[threadIdx.x] = 1.0f / (g[j + k] - g[j] + 1e-8f);
        }
        __syncthreads();

        const int idx2 = blockIdx.x * 256 + threadIdx.x;  // pair index
        const int e0 = idx2 * 2;                          // b*IN_F + i (i even)
        const int b = e0 >> 10;
        const int i = e0 & 1023;
        const float2 xv2 = *(const float2*)(x + e0);

        float bs[2][11];
#pragma unroll
        for (int u = 0; u < 2; ++u) {
            const float xv = u ? xv2.y : xv2.x;
#pragma unroll
            for (int j = 0; j < 11; ++j)
                bs[u][j] = (xv >= g[j] && xv < g[j + 1]) ? 1.0f : 0.0f;
#pragma unroll
            for (int k = 1; k <= 3; ++k) {
                const float* rk = &rec[(k - 1) * 11];
#pragma unroll
                for (int j = 0; j < 10; ++j) {
                    if (j <= 10 - k) {
                        bs[u][j] = (xv - g[j]) * rk[j] * bs[u][j]
                                 + (g[j + k + 1] - xv) * rk[j + 1] * bs[u][j + 1];
                    }
                }
            }
        }

        const float s0 = xv2.x / (1.0f + __expf(-xv2.x));
        const float s1 = xv2.y / (1.0f + __expf(-xv2.y));

        bf16* rowp = A + (size_t)b * KDIM;
        *(bf16x2*)&rowp[i] = (bf16x2){(bf16)s0, (bf16)s1};
#pragma unroll
        for (int j = 0; j < NSPLINE; ++j)
            *(bf16x2*)&rowp[(size_t)(j + 1) * IN_F + i] =
                (bf16x2){(bf16)bs[0][j], (bf16)bs[1][j]};
    } else {
        // ---------------- pack_W (2 elements/thread) ----------------
        const int idx2 = (blockIdx.x - NB_BUILD) * 256 + threadIdx.x;
        const int e0 = idx2 * 2;                          // o*IN_F + i (i even)
        const int i = e0 & 1023;
        const float2 s2 = *(const float2*)(sc + e0);
        const float2 bw2 = *(const float2*)(bw + e0);

        bf16* rowp = W + (size_t)(e0 >> 10) * KDIM;
        *(bf16x2*)&rowp[i] = (bf16x2){(bf16)bw2.x, (bf16)bw2.y};

        const float4* swv = (const float4*)(sw + (size_t)e0 * NSPLINE);
        const float4 a0 = swv[0], a1 = swv[1];   // element e0
        const float4 c0 = swv[2], c1 = swv[3];   // element e0+1
        float w0[NSPLINE] = {a0.x, a0.y, a0.z, a0.w, a1.x, a1.y, a1.z, a1.w};
        float w1[NSPLINE] = {c0.x, c0.y, c0.z, c0.w, c1.x, c1.y, c1.z, c1.w};
#pragma unroll
        for (int j = 0; j < NSPLINE; ++j)
            *(bf16x2*)&rowp[(size_t)(j + 1) * IN_F + i] =
                (bf16x2){(bf16)(w0[j] * s2.x), (bf16)(w1[j] * s2.y)};
    }
}

// -------------------------------------------------------------------------
// Kernel 2: 256x128x32 split-K GEMM, 2 blocks/CU, 3-slot ring + counted
// vmcnt (r16 occupancy + r12 pipeline depth).
// 512 threads = 8 waves (2M x 4N); per-wave output 128x32 (acc[8][2]).
// LDS 72 KB: A ring 3 x [256][32] (16 KB), B ring 3 x [128][32] (8 KB)
// -> 2 blocks/CU (144 KB LDS, 16 waves/CU). Stage lead +2 tiles; per-tile
// vmcnt(3) (3 gloads/tile in flight) -> tile t+1 guaranteed landed, never
// a mid-loop drain (r16's defect). Loop unrolled x3 -> literal slots.
//
// Hazards: tile t reads slot t%3 after a barrier preceded by ALL waves'
// vmcnt(3) (stage(t+1) retired => stage(t) long since). Slot t%3 is
// overwritten by stage(t+3), issued in tile t+1 AFTER the tile-t barrier
// that postdates every tile-t read. T2 swizzle + pre-permuted source
// byte-identical to r12/r16 (0 conflicts verified).
// -------------------------------------------------------------------------
#define BM8 256
#define BN8 128
#define BK8 32
#define SPLIT 4
#define KLEN (KDIM / SPLIT)   // 2304
#define NT8  (KLEN / BK8)     // 72 (divisible by 3)

#define GLOAD_LDS16(gp, lp)                                                          \
    __builtin_amdgcn_global_load_lds((const __attribute__((address_space(1))) void*)(gp), \
                                     (__attribute__((address_space(3))) void*)(lp), 16, 0, 0)

__global__ __launch_bounds__(512, 4) void gemm8(const bf16* __restrict__ A,
                                                const bf16* __restrict__ B,
                                                float* __restrict__ C)
{
    __shared__ bf16 lds[36864];   // A: 3 x 8192 elems; B at 24576: 3 x 4096

    const int tid  = threadIdx.x;
    const int wave = tid >> 6;
    const int lane = tid & 63;

    // bijective XCD swizzle (gridDim.x = 512, %8 == 0)
    const int nwg  = gridDim.x;
    const int q    = nwg >> 3;
    const int wgid = (blockIdx.x & 7) * q + (blockIdx.x >> 3);
    const int nxy  = (BATCH / BM8) * (OUT_F / BN8);   // 16*8 = 128
    const int z    = wgid / nxy;
    const int rem  = wgid - z * nxy;
    const int by   = rem >> 4;           // 0..7  (N tile)
    const int bx   = rem & 15;           // 0..15 (M tile)

    const int bm   = bx * BM8;
    const int bcol = by * BN8;
    const int kBase = z * KLEN;
    C += (size_t)z * BATCH * OUT_F;      // partial buffer for this K-slice

    const int wr = (wave >> 2) * 128;    // 2 M-waves
    const int wc = (wave & 3) * 32;      // 4 N-waves

    f32x4 acc[8][2] = {};

    // staging: thread covers row tid/4; global k-chunk pre-swizzled (T2/rule21)
    const int srow = tid >> 2;           // 0..127
    const int sch  = (((tid & 3) ^ ((tid >> 3) & 3))) * 8;
    const bf16* pA0 = A + (size_t)(bm + srow) * KDIM + kBase + sch;
    const bf16* pA1 = pA0 + (size_t)128 * KDIM;
    const bf16* pB0 = B + (size_t)(bcol + srow) * KDIM + kBase + sch;
    bf16* ldswA = lds + wave * 512;
    bf16* ldswB = lds + 24576 + wave * 512;

    // prologue: tiles 0,1 into slots 0,1; vmcnt(3) -> tile 0 landed
    GLOAD_LDS16(pA0, ldswA);
    GLOAD_LDS16(pA1, ldswA + 4096);
    GLOAD_LDS16(pB0, ldswB);
    GLOAD_LDS16(pA0 + BK8, ldswA + 8192);
    GLOAD_LDS16(pA1 + BK8, ldswA + 8192 + 4096);
    GLOAD_LDS16(pB0 + BK8, ldswB + 4096);
    asm volatile("s_waitcnt vmcnt(3)" ::: "memory");
    __builtin_amdgcn_s_barrier();

    const int rowk = lane & 15;
    const int kc   = lane >> 4;
    const int kxor = (kc ^ ((rowk >> 1) & 3)) * 8;   // T2 swizzle (verified r4-r16)

#define LDSA(s, row) (*(const bf16x8*)&lds[(s) * 8192 + (row) * 32 + kxor])
#define LDSB(s, row) (*(const bf16x8*)&lds[24576 + (s) * 4096 + (row) * 32 + kxor])

    // Tile body: slot S = t%3 (literal), staging target SN = (t+2)%3 (literal)
#define TILE(T, S, SN)                                                          \
  {                                                                             \
    bf16x8 a[4], b[2], a2[4];                                                   \
    if ((T) + 2 < NT8) {                                                        \
        GLOAD_LDS16(pA0 + ((T) + 2) * BK8, ldswA + (SN) * 8192);                \
        GLOAD_LDS16(pA1 + ((T) + 2) * BK8, ldswA + (SN) * 8192 + 4096);         \
    }                                                                           \
    _Pragma("unroll") for (int m = 0; m < 4; ++m) a[m] = LDSA(S, wr + m * 16 + rowk); \
    _Pragma("unroll") for (int n = 0; n < 2; ++n) b[n] = LDSB(S, wc + n * 16 + rowk); \
    if ((T) + 2 < NT8) GLOAD_LDS16(pB0 + ((T) + 2) * BK8, ldswB + (SN) * 4096); \
    _Pragma("unroll") for (int m = 0; m < 4; ++m) a2[m] = LDSA(S, wr + 64 + m * 16 + rowk); \
    __builtin_amdgcn_sched_barrier(0);                                          \
    __builtin_amdgcn_s_setprio(1);                                              \
    _Pragma("unroll") for (int m = 0; m < 4; ++m)                               \
    _Pragma("unroll") for (int n = 0; n < 2; ++n)                               \
        acc[m][n] = __builtin_amdgcn_mfma_f32_16x16x32_bf16(a[m], b[n], acc[m][n], 0, 0, 0); \
    _Pragma("unroll") for (int m = 0; m < 4; ++m)                               \
    _Pragma("unroll") for (int n = 0; n < 2; ++n)                               \
        acc[4 + m][n] = __builtin_amdgcn_mfma_f32_16x16x32_bf16(a2[m], b[n], acc[4 + m][n], 0, 0, 0); \
    __builtin_amdgcn_s_setprio(0);                                              \
    if ((T) < NT8 - 3)       asm volatile("s_waitcnt vmcnt(3)" ::: "memory");   \
    else if ((T) == NT8 - 3) asm volatile("s_waitcnt vmcnt(0)" ::: "memory");   \
    __builtin_amdgcn_s_barrier();                                               \
  }

    for (int tt = 0; tt < NT8; tt += 3) {
        TILE(tt,     0, 2)
        TILE(tt + 1, 1, 0)
        TILE(tt + 2, 2, 1)
    }
#undef TILE
#undef LDSA
#undef LDSB

    // epilogue: C/D layout col = lane&15, row = (lane>>4)*4 + r
    const int ccol = lane & 15;
    const int crow = (lane >> 4) * 4;
#pragma unroll
    for (int mf = 0; mf < 8; ++mf) {
#pragma unroll
        for (int nf = 0; nf < 2; ++nf) {
            float* cp = C + (size_t)(bm + wr + mf * 16 + crow) * OUT_F + (bcol + wc + nf * 16 + ccol);
#pragma unroll
            for (int r = 0; r < 4; ++r)
                cp[(size_t)r * OUT_F] = acc[mf][nf][r];
        }
    }
}

// -------------------------------------------------------------------------
// Kernel 3: sum SPLIT partial C buffers into out (float4-vectorized).
// -------------------------------------------------------------------------
__global__ __launch_bounds__(256) void reduce_partials(const float4* __restrict__ P,
                                                       float4* __restrict__ out,
                                                       int n4)
{
    const int stride = gridDim.x * 256;
    for (int i = blockIdx.x * 256 + threadIdx.x; i < n4; i += stride) {
        float4 s = P[i];
#pragma unroll
        for (int p = 1; p < SPLIT; ++p) {
            const float4 q = P[(size_t)p * n4 + i];
            s.x += q.x; s.y += q.y; s.z += q.z; s.w += q.w;
        }
        out[i] = s;
    }
}

// -------------------------------------------------------------------------
extern "C" void kernel_launch(void* const* d_in, const int* in_sizes, int n_in,
                              void* d_out, int out_size, void* d_ws, size_t ws_size,
                              hipStream_t stream)
{
    const float* x  = (const float*)d_in[0];   // (4096,1024)
    const float* bw = (const float*)d_in[1];   // (1024,1024)
    const float* sw = (const float*)d_in[2];   // (1024,1024,8)
    const float* sc = (const float*)d_in[3];   // (1024,1024)
    const float* gr = (const float*)d_in[4];   // (1024,12) all rows equal
    float* out = (float*)d_out;                // (4096,1024)

    bf16* A = (bf16*)d_ws;                          // 4096*9216*2 = 75.5 MB
    bf16* W = A + (size_t)BATCH * KDIM;             // 1024*9216*2 = 18.9 MB
    float* parts = (float*)(W + (size_t)OUT_F * KDIM);   // 4 x 16.8 MB

    prep<<<NB_BUILD + NB_PACK, 256, 0, stream>>>(x, gr, bw, sw, sc, A, W);

    const int nblk = (BATCH / BM8) * (OUT_F / BN8) * SPLIT;   // 512
    gemm8<<<nblk, 512, 0, stream>>>(A, W, parts);

    const int n4 = BATCH * OUT_F / 4;
    reduce_partials<<<2048, 256, 0, stream>>>((const float4*)parts, (float4*)out, n4);
}

// Round 18
// 121.042 us; speedup vs baseline: 1.0687x; 1.0687x over previous
//
#include <hip/hip_runtime.h>
#include <hip/hip_bf16.h>
#include <stdint.h>
#include <stddef.h>

// Problem constants (from reference)
#define IN_F     1024
#define OUT_F    1024
#define BATCH    4096
#define NSPLINE  8            // GRID_SIZE + SPLINE_ORDER
#define KDIM     (IN_F * 9)   // 9216 : plane 0 = silu(x), planes 1..8 = spline basis
#define GRIDPTS  12           // GRID_SIZE + 2*SPLINE_ORDER + 1

typedef __bf16 bf16;
typedef __bf16 bf16x2 __attribute__((ext_vector_type(2)));
typedef __bf16 bf16x8 __attribute__((ext_vector_type(8)));
typedef float  f32x4  __attribute__((ext_vector_type(4)));

// -------------------------------------------------------------------------
// Kernel 1 (fused prep), vectorized bf16x2 stores (r15, verified).
// -------------------------------------------------------------------------
#define NB_BUILD (BATCH * IN_F / 512)   // 8192
#define NB_PACK  (OUT_F * IN_F / 512)   // 2048

__global__ __launch_bounds__(256) void prep(const float* __restrict__ x,
                                            const float* __restrict__ grid,
                                            const float* __restrict__ bw,
                                            const float* __restrict__ sw,
                                            const float* __restrict__ sc,
                                            bf16* __restrict__ A,
                                            bf16* __restrict__ W)
{
    __shared__ float g[GRIDPTS];
    __shared__ float rec[33];   // rec[(k-1)*11 + j] = 1/(g[j+k]-g[j]+1e-8)

    if (blockIdx.x < NB_BUILD) {
        // ---------------- build_A (2 elements/thread) ----------------
        if (threadIdx.x < GRIDPTS) g[threadIdx.x] = grid[threadIdx.x];  // row 0
        __syncthreads();
        if (threadIdx.x < 33) {
            const int k = threadIdx.x / 11 + 1;
            const int j = threadIdx.x % 11;
            if (j + k <= 11) rec[threadIdx.x] = 1.0f / (g[j + k] - g[j] + 1e-8f);
        }
        __syncthreads();

        const int idx2 = blockIdx.x * 256 + threadIdx.x;  // pair index
        const int e0 = idx2 * 2;                          // b*IN_F + i (i even)
        const int b = e0 >> 10;
        const int i = e0 & 1023;
        const float2 xv2 = *(const float2*)(x + e0);

        float bs[2][11];
#pragma unroll
        for (int u = 0; u < 2; ++u) {
            const float xv = u ? xv2.y : xv2.x;
#pragma unroll
            for (int j = 0; j < 11; ++j)
                bs[u][j] = (xv >= g[j] && xv < g[j + 1]) ? 1.0f : 0.0f;
#pragma unroll
            for (int k = 1; k <= 3; ++k) {
                const float* rk = &rec[(k - 1) * 11];
#pragma unroll
                for (int j = 0; j < 10; ++j) {
                    if (j <= 10 - k) {
                        bs[u][j] = (xv - g[j]) * rk[j] * bs[u][j]
                                 + (g[j + k + 1] - xv) * rk[j + 1] * bs[u][j + 1];
                    }
                }
            }
        }

        const float s0 = xv2.x / (1.0f + __expf(-xv2.x));
        const float s1 = xv2.y / (1.0f + __expf(-xv2.y));

        bf16* rowp = A + (size_t)b * KDIM;
        *(bf16x2*)&rowp[i] = (bf16x2){(bf16)s0, (bf16)s1};
#pragma unroll
        for (int j = 0; j < NSPLINE; ++j)
            *(bf16x2*)&rowp[(size_t)(j + 1) * IN_F + i] =
                (bf16x2){(bf16)bs[0][j], (bf16)bs[1][j]};
    } else {
        // ---------------- pack_W (2 elements/thread) ----------------
        const int idx2 = (blockIdx.x - NB_BUILD) * 256 + threadIdx.x;
        const int e0 = idx2 * 2;                          // o*IN_F + i (i even)
        const int i = e0 & 1023;
        const float2 s2 = *(const float2*)(sc + e0);
        const float2 bw2 = *(const float2*)(bw + e0);

        bf16* rowp = W + (size_t)(e0 >> 10) * KDIM;
        *(bf16x2*)&rowp[i] = (bf16x2){(bf16)bw2.x, (bf16)bw2.y};

        const float4* swv = (const float4*)(sw + (size_t)e0 * NSPLINE);
        const float4 a0 = swv[0], a1 = swv[1];   // element e0
        const float4 c0 = swv[2], c1 = swv[3];   // element e0+1
        float w0[NSPLINE] = {a0.x, a0.y, a0.z, a0.w, a1.x, a1.y, a1.z, a1.w};
        float w1[NSPLINE] = {c0.x, c0.y, c0.z, c0.w, c1.x, c1.y, c1.z, c1.w};
#pragma unroll
        for (int j = 0; j < NSPLINE; ++j)
            *(bf16x2*)&rowp[(size_t)(j + 1) * IN_F + i] =
                (bf16x2){(bf16)(w0[j] * s2.x), (bf16)(w1[j] * s2.y)};
    }
}

// -------------------------------------------------------------------------
// Kernel 2: 256x256x64 pipelined 4-phase split-K GEMM (T1+T2+T4+T5).
// r12 verbatim — thrice-verified optimum: 78.5-79.3 us, 0 bank conflicts,
// MfmaUtil 40%, VGPR 104, FETCH 83 MB. Ring of 8 LDS half-slots, counted
// vmcnt (never 0 mid-loop), cross-phase ds_read pipelining, T2 chunk-XOR
// swizzle with pre-permuted global source (rule #21).
// -------------------------------------------------------------------------
#define BM8 256
#define BN8 256
#define BK8 64
#define SPLIT 4

#define GLOAD_LDS16(gp, lp)                                                          \
    __builtin_amdgcn_global_load_lds((const __attribute__((address_space(1))) void*)(gp), \
                                     (__attribute__((address_space(3))) void*)(lp), 16, 0, 0)

__global__ __launch_bounds__(512, 2) void gemm8(const bf16* __restrict__ A,
                                                const bf16* __restrict__ B,
                                                float* __restrict__ C,
                                                int kLen)
{
    __shared__ bf16 lds[8 * 8192];   // 8 half-slots x 16 KB = 128 KB

    const int tid  = threadIdx.x;
    const int wave = tid >> 6;
    const int lane = tid & 63;

    // bijective XCD swizzle (gridDim.x % 8 == 0)
    const int nwg  = gridDim.x;
    const int q    = nwg >> 3;
    const int wgid = (blockIdx.x & 7) * q + (blockIdx.x >> 3);
    const int nxy  = (BATCH / BM8) * (OUT_F / BN8);   // 16*4 = 64
    const int z    = wgid / nxy;
    const int rem  = wgid - z * nxy;
    const int by   = rem >> 4;           // 0..3
    const int bx   = rem & 15;           // 0..15

    const int bm   = bx * BM8;
    const int bcol = by * BN8;
    const int kBase = z * kLen;
    C += (size_t)z * BATCH * OUT_F;      // partial buffer for this K-slice

    const int wr = (wave >> 2) * 128;    // 2 M-waves
    const int wc = (wave & 3) * 64;      // 4 N-waves

    f32x4 acc[8][4] = {};

    const int NT   = kLen / BK8;
    const int hmax = 4 * NT;

    // staging geometry: thread covers row tid/4; global k-chunk pre-swizzled
    // so the linear LDS write lands data where the swizzled reader expects.
    const int srow = tid >> 2;           // 0..127
    const int sch  = (((tid & 3) ^ ((tid >> 3) & 3))) * 8;
    const bf16* baseA = A + (size_t)(bm + srow) * KDIM + kBase + sch;
    const bf16* baseB = B + (size_t)(bcol + srow) * KDIM + kBase + sch;
    const size_t rstep = (size_t)128 * KDIM;
    bf16* ldsw = &lds[wave * 512];       // wave-uniform dest segment

    auto stage = [&](int h) {
        if (h < hmax) {
            const int t   = h >> 2;
            const int th  = h & 3;
            const int kof = t * BK8 + ((th >> 1) ? 32 : 0);
            const bf16* src = (th & 1) ? baseB : baseA;
            bf16* l0 = ldsw + (h & 7) * 8192;
            GLOAD_LDS16(src + kof, l0);
            GLOAD_LDS16(src + kof + rstep, l0 + 4096);
        }
    };

    // prologue: stage halves 0..5; vmcnt(4) -> halves 0..3 landed; barrier
    for (int h = 0; h < 6; ++h) stage(h);
    asm volatile("s_waitcnt vmcnt(4)" ::: "memory");
    __builtin_amdgcn_s_barrier();

    const int rowk = lane & 15;
    const int kc   = lane >> 4;          // logical 8-elem k-chunk 0..3
    // (row>>1)&3 == (rowk>>1)&3 for all rows we touch (wr,wc,m*16 ≡ 0 mod 8)
    const int kxor = (kc ^ ((rowk >> 1) & 3)) * 8;

#define LDSFRAG(slot, row) (*(const bf16x8*)&lds[(slot) * 8192 + (row) * 32 + kxor])

    bf16x8 a[4], b[4], a2[4], b2[4];
    // initial reads: tile 0 phase 1 operands (slots 0 = A-kh0, 1 = B-kh0)
#pragma unroll
    for (int m = 0; m < 4; ++m) a[m] = LDSFRAG(0, wr + m * 16 + rowk);
#pragma unroll
    for (int n = 0; n < 4; ++n) b[n] = LDSFRAG(1, wc + n * 16 + rowk);

    for (int t = 0; t < NT; ++t) {
        const int h0  = 4 * t;
        const int sA0 = (h0 + 0) & 7;
        const int sA1 = (h0 + 2) & 7, sB1 = (h0 + 3) & 7;

        // ---- phase 1: acc_lo += a(kh0,Mlow) x b(kh0); prefetch a2 = kh0,Mhigh
        stage(h0 + 6);
#pragma unroll
        for (int m = 0; m < 4; ++m) a2[m] = LDSFRAG(sA0, wr + 64 + m * 16 + rowk);
        __builtin_amdgcn_sched_barrier(0);
        __builtin_amdgcn_s_setprio(1);
#pragma unroll
        for (int m = 0; m < 4; ++m)
#pragma unroll
            for (int n = 0; n < 4; ++n)
                acc[m][n] = __builtin_amdgcn_mfma_f32_16x16x32_bf16(a[m], b[n], acc[m][n], 0, 0, 0);
        __builtin_amdgcn_s_setprio(0);
        __builtin_amdgcn_s_barrier();

        // ---- phase 2: acc_hi += a2 x b; prefetch a = kh1,Mlow and b2 = kh1
        stage(h0 + 7);
#pragma unroll
        for (int m = 0; m < 4; ++m) a[m] = LDSFRAG(sA1, wr + m * 16 + rowk);
#pragma unroll
        for (int n = 0; n < 4; ++n) b2[n] = LDSFRAG(sB1, wc + n * 16 + rowk);
        __builtin_amdgcn_sched_barrier(0);
        __builtin_amdgcn_s_setprio(1);
#pragma unroll
        for (int m = 0; m < 4; ++m)
#pragma unroll
            for (int n = 0; n < 4; ++n)
                acc[4 + m][n] = __builtin_amdgcn_mfma_f32_16x16x32_bf16(a2[m], b[n], acc[4 + m][n], 0, 0, 0);
        __builtin_amdgcn_s_setprio(0);
        __builtin_amdgcn_s_barrier();

        // ---- phase 3: acc_lo += a x b2; prefetch a2 = kh1,Mhigh
        stage(h0 + 8);
#pragma unroll
        for (int m = 0; m < 4; ++m) a2[m] = LDSFRAG(sA1, wr + 64 + m * 16 + rowk);
        __builtin_amdgcn_sched_barrier(0);
        __builtin_amdgcn_s_setprio(1);
#pragma unroll
        for (int m = 0; m < 4; ++m)
#pragma unroll
            for (int n = 0; n < 4; ++n)
                acc[m][n] = __builtin_amdgcn_mfma_f32_16x16x32_bf16(a[m], b2[n], acc[m][n], 0, 0, 0);
        __builtin_amdgcn_s_setprio(0);
        __builtin_amdgcn_s_barrier();

        // ---- phase 4: acc_hi += a2 x b2; vmcnt; prefetch next tile's a,b
        stage(h0 + 9);
        __builtin_amdgcn_sched_barrier(0);
        __builtin_amdgcn_s_setprio(1);
#pragma unroll
        for (int m = 0; m < 4; ++m)
#pragma unroll
            for (int n = 0; n < 4; ++n)
                acc[4 + m][n] = __builtin_amdgcn_mfma_f32_16x16x32_bf16(a2[m], b2[n], acc[4 + m][n], 0, 0, 0);
        __builtin_amdgcn_s_setprio(0);
        // counted per-tile wait: halves <= 4t+7 landed; never drain mid-loop
        if (t < NT - 2)       asm volatile("s_waitcnt vmcnt(4)" ::: "memory");
        else if (t == NT - 2) asm volatile("s_waitcnt vmcnt(0)" ::: "memory");
        if (t + 1 < NT) {
            const int nA0 = (h0 + 4) & 7, nB0 = (h0 + 5) & 7;
#pragma unroll
            for (int m = 0; m < 4; ++m) a[m] = LDSFRAG(nA0, wr + m * 16 + rowk);
#pragma unroll
            for (int n = 0; n < 4; ++n) b[n] = LDSFRAG(nB0, wc + n * 16 + rowk);
        }
        __builtin_amdgcn_s_barrier();
    }
#undef LDSFRAG

    // epilogue: C/D layout col = lane&15, row = (lane>>4)*4 + r
    const int ccol = lane & 15;
    const int crow = (lane >> 4) * 4;
#pragma unroll
    for (int mf = 0; mf < 8; ++mf) {
#pragma unroll
        for (int nf = 0; nf < 4; ++nf) {
            float* cp = C + (size_t)(bm + wr + mf * 16 + crow) * OUT_F + (bcol + wc + nf * 16 + ccol);
#pragma unroll
            for (int r = 0; r < 4; ++r)
                cp[(size_t)r * OUT_F] = acc[mf][nf][r];
        }
    }
}

// -------------------------------------------------------------------------
// Kernel 3: sum SPLIT partial C buffers into out (float4-vectorized).
// -------------------------------------------------------------------------
__global__ __launch_bounds__(256) void reduce_partials(const float4* __restrict__ P,
                                                       float4* __restrict__ out,
                                                       int n4)
{
    const int stride = gridDim.x * 256;
    for (int i = blockIdx.x * 256 + threadIdx.x; i < n4; i += stride) {
        float4 s = P[i];
#pragma unroll
        for (int p = 1; p < SPLIT; ++p) {
            const float4 q = P[(size_t)p * n4 + i];
            s.x += q.x; s.y += q.y; s.z += q.z; s.w += q.w;
        }
        out[i] = s;
    }
}

// -------------------------------------------------------------------------
extern "C" void kernel_launch(void* const* d_in, const int* in_sizes, int n_in,
                              void* d_out, int out_size, void* d_ws, size_t ws_size,
                              hipStream_t stream)
{
    const float* x  = (const float*)d_in[0];   // (4096,1024)
    const float* bw = (const float*)d_in[1];   // (1024,1024)
    const float* sw = (const float*)d_in[2];   // (1024,1024,8)
    const float* sc = (const float*)d_in[3];   // (1024,1024)
    const float* gr = (const float*)d_in[4];   // (1024,12) all rows equal
    float* out = (float*)d_out;                // (4096,1024)

    bf16* A = (bf16*)d_ws;                          // 4096*9216*2 = 75.5 MB
    bf16* W = A + (size_t)BATCH * KDIM;             // 1024*9216*2 = 18.9 MB
    float* parts = (float*)(W + (size_t)OUT_F * KDIM);   // 4 x 16.8 MB

    prep<<<NB_BUILD + NB_PACK, 256, 0, stream>>>(x, gr, bw, sw, sc, A, W);

    const int nblk = (BATCH / BM8) * (OUT_F / BN8) * SPLIT;   // 256
    gemm8<<<nblk, 512, 0, stream>>>(A, W, parts, KDIM / SPLIT);

    const int n4 = BATCH * OUT_F / 4;
    reduce_partials<<<2048, 256, 0, stream>>>((const float4*)parts, (float4*)out, n4);
}